// Round 1
// baseline (185.982 us; speedup 1.0000x reference)
//
#include <hip/hip_runtime.h>
#include <math.h>

// Problem geometry (fixed by reference): input (32,3,128,128) f32,
// output (32,3,512,512) f32 -> bicubic 4x downsample of output, mean |diff|.
#define BCN   96
#define IN_H  512
#define IN_W  512
#define OUT_H 128
#define OUT_W 128
#define TAPS  16
#define PAD   6
#define STRIDE 4
#define TR    8                      // output rows per block
#define IR    ((TR - 1) * STRIDE + TAPS)   // 44 input rows needed per tile
#define NBLK  (BCN * (OUT_H / TR))   // 96 * 16 = 1536 blocks
#define TOTAL_ELEMS (BCN * OUT_H * OUT_W)  // 1572864

struct K16 { float w[TAPS]; };

__device__ __forceinline__ int sym_idx(int i, int n) {
    // 'symmetric' pad reflection (edge included)
    i = (i < 0) ? (-1 - i) : i;
    i = (i >= n) ? (2 * n - 1 - i) : i;
    return i;
}

__global__ __launch_bounds__(256)
void bploss_kernel(const float* __restrict__ input,   // (96,128,128)
                   const float* __restrict__ outimg,  // (96,512,512)
                   float* __restrict__ loss, K16 kw)
{
    __shared__ float hbuf[IR * OUT_W];   // 44*128*4 = 22528 B
    __shared__ float wsum[4];

    const int tid  = threadIdx.x;
    const int bc   = blockIdx.x >> 4;    // / (OUT_H/TR)
    const int tile = blockIdx.x & 15;
    const int r0   = tile * TR;          // first output row of this tile
    const int iy0  = r0 * STRIDE - PAD;  // first (virtual) input row needed

    const float* img = outimg + (size_t)bc * IN_H * IN_W;

    // ---- Phase 1: horizontal 16-tap conv for IR rows -> hbuf[rr][xo] ----
    // IR*OUT_W = 5632 = 22 * 256 exactly.
    #pragma unroll 2
    for (int f = tid; f < IR * OUT_W; f += 256) {
        const int rr = f >> 7;           // /128
        const int xo = f & 127;
        const int y  = sym_idx(iy0 + rr, IN_H);
        const float* row = img + (size_t)y * IN_W;
        const int xb = xo * STRIDE - PAD;
        float acc = 0.0f;
        if (xb >= 0 && xb + TAPS <= IN_W) {
            // row+xb is 8B-aligned (byte off = 16*xo - 24 ≡ 8 mod 16)
            const float2* p = reinterpret_cast<const float2*>(row + xb);
            #pragma unroll
            for (int t = 0; t < TAPS / 2; ++t) {
                float2 v = p[t];
                acc += kw.w[2 * t] * v.x + kw.w[2 * t + 1] * v.y;
            }
        } else {
            #pragma unroll
            for (int t = 0; t < TAPS; ++t) {
                const int x = sym_idx(xb + t, IN_W);
                acc += kw.w[t] * row[x];
            }
        }
        hbuf[f] = acc;
    }
    __syncthreads();

    // ---- Phase 2: vertical 16-tap conv + |diff| + reduction ----
    float lsum = 0.0f;
    #pragma unroll
    for (int it = 0; it < (TR * OUT_W) / 256; ++it) {  // 4 outputs/thread
        const int g  = tid + it * 256;
        const int yl = g >> 7;           // local output row 0..7
        const int x  = g & 127;
        const float* hb = &hbuf[yl * STRIDE * OUT_W + x];
        float acc = 0.0f;
        #pragma unroll
        for (int t = 0; t < TAPS; ++t) acc += kw.w[t] * hb[t * OUT_W];
        const int yo = r0 + yl;
        const float ref = input[((size_t)bc * OUT_H + yo) * OUT_W + x];
        lsum += fabsf(acc - ref);
    }

    // wave (64-lane) butterfly reduce
    #pragma unroll
    for (int off = 32; off > 0; off >>= 1)
        lsum += __shfl_down(lsum, off, 64);

    const int wid = tid >> 6, lane = tid & 63;
    if (lane == 0) wsum[wid] = lsum;
    __syncthreads();
    if (tid == 0) {
        const float s = wsum[0] + wsum[1] + wsum[2] + wsum[3];
        atomicAdd(loss, s * (1.0f / (float)TOTAL_ELEMS));
    }
}

static void make_weights(K16* kw) {
    // Matches reference _make_kernel(512,128): tap t at x=(7.5-t)*0.25,
    // cubic window, normalized in f64 then cast to f32 (scale factor cancels).
    const double scale = 0.25;
    double w[TAPS]; double s = 0.0;
    for (int t = 0; t < TAPS; ++t) {
        const double ax = fabs((7.5 - (double)t) * scale);
        double v;
        if (ax <= 1.0)      v = 1.5 * ax * ax * ax - 2.5 * ax * ax + 1.0;
        else if (ax <= 2.0) v = -0.5 * ax * ax * ax + 2.5 * ax * ax - 4.0 * ax + 2.0;
        else                v = 0.0;
        w[t] = v * scale; s += w[t];
    }
    for (int t = 0; t < TAPS; ++t) kw->w[t] = (float)(w[t] / s);
}

extern "C" void kernel_launch(void* const* d_in, const int* in_sizes, int n_in,
                              void* d_out, int out_size, void* d_ws, size_t ws_size,
                              hipStream_t stream) {
    // dict order: 'input' (1572864), 'output' (25165824); guard by size anyway.
    const float* input;
    const float* outimg;
    if (in_sizes[0] == TOTAL_ELEMS) {
        input  = (const float*)d_in[0];
        outimg = (const float*)d_in[1];
    } else {
        input  = (const float*)d_in[1];
        outimg = (const float*)d_in[0];
    }
    float* loss = (float*)d_out;

    K16 kw;
    make_weights(&kw);

    hipMemsetAsync(d_out, 0, sizeof(float), stream);   // d_out is poisoned 0xAA
    bploss_kernel<<<NBLK, 256, 0, stream>>>(input, outimg, loss, kw);
}

// Round 2
// 166.722 us; speedup vs baseline: 1.1155x; 1.1155x over previous
//
#include <hip/hip_runtime.h>
#include <math.h>

// input (32,3,128,128) f32; output (32,3,512,512) f32.
// loss = mean |bicubic_down4(output) - input|, 16-tap separable, symmetric pad 6.
#define BCN   96
#define IN_H  512
#define IN_W  512
#define OUT_H 128
#define OUT_W 128
#define TAPS  16
#define PAD   6
#define STRIDE 4
#define TR    8                          // output rows per block
#define IR    ((TR - 1) * STRIDE + TAPS) // 44 input rows per tile
#define NBLK  (BCN * (OUT_H / TR))       // 1536 blocks
#define TOTAL_ELEMS (BCN * OUT_H * OUT_W)

struct K16 { float w[TAPS]; };

__device__ __forceinline__ int sym_idx(int i, int n) {
    i = (i < 0) ? (-1 - i) : i;
    i = (i >= n) ? (2 * n - 1 - i) : i;
    return i;
}

__global__ __launch_bounds__(256)
void bploss_kernel(const float* __restrict__ input,   // (96,128,128)
                   const float* __restrict__ outimg,  // (96,512,512)
                   float* __restrict__ loss, K16 kw)
{
    __shared__ float hbuf[IR * OUT_W];   // 22528 B
    __shared__ float wsum[4];

    const int tid  = threadIdx.x;
    const int bc   = blockIdx.x >> 4;
    const int tile = blockIdx.x & 15;
    const int r0   = tile * TR;
    const int iy0  = r0 * STRIDE - PAD;

    const float* img = outimg + (size_t)bc * IN_H * IN_W;

    // ---- Phase 1: horizontal conv. 2 adjacent cols/thread from one aligned
    // 24-float window; 4 rows per pass, 11 passes. NO divergence in the loop:
    // boundary cols (0,1,126,127 — the only ones needing reflection) are
    // recomputed in a uniform fixup pass below.
    const int pr = tid >> 6;             // row-in-pass 0..3
    const int c  = tid & 63;             // col-pair index (xo = 2c, 2c+1)
    int base = 8 * c - 8;                // window start (16B-aligned)
    base = (base < 0) ? 0 : base;        // c==0  (garbage, fixed up)
    base = (base > 488) ? 488 : base;    // c==63 (garbage, fixed up; stays in-bounds)

    #pragma unroll 2
    for (int it = 0; it < IR / 4; ++it) {
        const int rr = pr + 4 * it;
        const int y  = sym_idx(iy0 + rr, IN_H);
        const float4* p = reinterpret_cast<const float4*>(img + (size_t)y * IN_W + base);
        const float4 v0 = p[0], v1 = p[1], v2 = p[2], v3 = p[3], v4 = p[4], v5 = p[5];
        const float win[24] = { v0.x, v0.y, v0.z, v0.w,  v1.x, v1.y, v1.z, v1.w,
                                v2.x, v2.y, v2.z, v2.w,  v3.x, v3.y, v3.z, v3.w,
                                v4.x, v4.y, v4.z, v4.w,  v5.x, v5.y, v5.z, v5.w };
        float acc0 = 0.0f, acc1 = 0.0f;
        #pragma unroll
        for (int t = 0; t < TAPS; ++t) {
            acc0 += kw.w[t] * win[t + 2];   // xo = 2c   : row[8c-6+t]
            acc1 += kw.w[t] * win[t + 6];   // xo = 2c+1 : row[8c-2+t]
        }
        reinterpret_cast<float2*>(hbuf)[rr * 64 + c] = make_float2(acc0, acc1);
    }
    __syncthreads();

    // ---- Fixup: boundary columns, 44 rows x {0,1,126,127} = 176 outputs ----
    if (tid < IR * 4) {
        const int rr = tid >> 2;
        const int ci = tid & 3;
        const int xo = (ci < 2) ? ci : (124 + ci);   // 0,1,126,127
        const int y  = sym_idx(iy0 + rr, IN_H);
        const float* row = img + (size_t)y * IN_W;
        float acc = 0.0f;
        #pragma unroll
        for (int t = 0; t < TAPS; ++t)
            acc += kw.w[t] * row[sym_idx(xo * STRIDE - PAD + t, IN_W)];
        hbuf[rr * OUT_W + xo] = acc;
    }
    __syncthreads();

    // ---- Phase 2: vertical conv + |diff| + reduction ----
    float lsum = 0.0f;
    #pragma unroll
    for (int itr = 0; itr < (TR * OUT_W) / 256; ++itr) {   // 4 outputs/thread
        const int g  = tid + itr * 256;
        const int yl = g >> 7;
        const int x  = g & 127;
        const float* hb = &hbuf[yl * STRIDE * OUT_W + x];
        float acc = 0.0f;
        #pragma unroll
        for (int t = 0; t < TAPS; ++t) acc += kw.w[t] * hb[t * OUT_W];
        const int yo = r0 + yl;
        const float ref = input[((size_t)bc * OUT_H + yo) * OUT_W + x];
        lsum += fabsf(acc - ref);
    }

    #pragma unroll
    for (int off = 32; off > 0; off >>= 1)
        lsum += __shfl_down(lsum, off, 64);

    const int wid = tid >> 6, lane = tid & 63;
    if (lane == 0) wsum[wid] = lsum;
    __syncthreads();
    if (tid == 0) {
        const float s = wsum[0] + wsum[1] + wsum[2] + wsum[3];
        atomicAdd(loss, s * (1.0f / (float)TOTAL_ELEMS));
    }
}

static void make_weights(K16* kw) {
    const double scale = 0.25;
    double w[TAPS]; double s = 0.0;
    for (int t = 0; t < TAPS; ++t) {
        const double ax = fabs((7.5 - (double)t) * scale);
        double v;
        if (ax <= 1.0)      v = 1.5 * ax * ax * ax - 2.5 * ax * ax + 1.0;
        else if (ax <= 2.0) v = -0.5 * ax * ax * ax + 2.5 * ax * ax - 4.0 * ax + 2.0;
        else                v = 0.0;
        w[t] = v * scale; s += w[t];
    }
    for (int t = 0; t < TAPS; ++t) kw->w[t] = (float)(w[t] / s);
}

extern "C" void kernel_launch(void* const* d_in, const int* in_sizes, int n_in,
                              void* d_out, int out_size, void* d_ws, size_t ws_size,
                              hipStream_t stream) {
    const float* input;
    const float* outimg;
    if (in_sizes[0] == TOTAL_ELEMS) {
        input  = (const float*)d_in[0];
        outimg = (const float*)d_in[1];
    } else {
        input  = (const float*)d_in[1];
        outimg = (const float*)d_in[0];
    }
    float* loss = (float*)d_out;

    K16 kw;
    make_weights(&kw);

    hipMemsetAsync(d_out, 0, sizeof(float), stream);
    bploss_kernel<<<NBLK, 256, 0, stream>>>(input, outimg, loss, kw);
}